// Round 3
// baseline (160.718 us; speedup 1.0000x reference)
//
#include <hip/hip_runtime.h>
#include <hip/hip_bf16.h>

// Problem constants (T,S,W,D,C,K) = (16,16,10,512,64,512)
#define T_  16
#define W_  10
#define D_  512
#define SW_ 160      // S*W
#define N1_ 1024     // 2*D
#define KT_ 512      // triplets per (t,w)

typedef __bf16 bf16x8 __attribute__((ext_vector_type(8)));
typedef _Float16 f16x8 __attribute__((ext_vector_type(8)));
typedef _Float16 h2v  __attribute__((ext_vector_type(2)));
typedef float  f32x4  __attribute__((ext_vector_type(4)));

// async global->LDS, 16B per lane (global addr per-lane; LDS dest = wave base + lane*16)
__device__ __forceinline__ void async16(const void* g, void* l) {
  __builtin_amdgcn_global_load_lds(
      (__attribute__((address_space(1))) void*)(g),
      (__attribute__((address_space(3))) void*)(l), 16, 0, 0);
}

__device__ __forceinline__ h2v bc2(unsigned u) { return __builtin_bit_cast(h2v, u); }
// relu on packed fp16 pair (v_pk_max_f16 with inline 0)
__device__ __forceinline__ h2v relu2(h2v a) {
  h2v r;
  asm("v_pk_max_f16 %0, %1, 0" : "=v"(r) : "v"(a));
  return r;
}

// ================= K0: prep_all — every cast/transpose/bias-fold in ONE launch
// blocks: [0,1280) cast x(bf16) | [1280,2816) W1^T(bf16) | [2816,3328) W2 cast(fp16)
//         [3328,3840) W3^T(fp16) | [3840,4352) W4 cast(fp16) | [4352,4384) Wc^T(fp16)
//         [4384,4388) b23 = 512*b2@W3 + b3 | [4388] bc4 = b4@Wc + bc
__global__ __launch_bounds__(256) void prep_all(
    const float* __restrict__ x_in, const float* __restrict__ W1,
    const float* __restrict__ W2, const float* __restrict__ W3,
    const float* __restrict__ W4, const float* __restrict__ Wc,
    const float* __restrict__ b2, const float* __restrict__ b3,
    const float* __restrict__ b4, const float* __restrict__ bc,
    __hip_bfloat16* __restrict__ xbf, __hip_bfloat16* __restrict__ w1t,
    _Float16* __restrict__ w2b, _Float16* __restrict__ w3t,
    _Float16* __restrict__ w4b, _Float16* __restrict__ wct,
    float* __restrict__ b23, float* __restrict__ bc4)
{
  __shared__ float tile[32 * 33];
  const int b = blockIdx.x, tid = threadIdx.x;

  auto cast4h = [&](const float* src, _Float16* dst, int base) {
    int i = (base + tid) << 2;
    float4 v = *(const float4*)(src + i);
    __align__(8) _Float16 o4[4] = {(_Float16)v.x, (_Float16)v.y,
                                   (_Float16)v.z, (_Float16)v.w};
    *(uint2*)(dst + i) = *(const uint2*)o4;
  };
  auto tr32h = [&](const float* src, _Float16* dst, int R, int C, int rt, int ct) {
    int r0 = rt << 5, c0 = ct << 5;
    int c = tid & 31, rr = tid >> 5;
#pragma unroll
    for (int i = 0; i < 4; ++i) {
      int r = rr + i * 8;
      tile[r * 33 + c] = src[(size_t)(r0 + r) * C + c0 + c];
    }
    __syncthreads();
#pragma unroll
    for (int i = 0; i < 4; ++i) {
      int r = rr + i * 8;
      dst[(size_t)(c0 + r) * R + r0 + c] = (_Float16)tile[c * 33 + r];
    }
  };

  if (b < 1280) {
    int i = (b * 256 + tid) << 2;
    float4 v = *(const float4*)(x_in + i);
    __align__(8) __hip_bfloat16 o4[4];
    o4[0] = __float2bfloat16(v.x); o4[1] = __float2bfloat16(v.y);
    o4[2] = __float2bfloat16(v.z); o4[3] = __float2bfloat16(v.w);
    *(uint2*)(xbf + i) = *(const uint2*)o4;
  } else if (b < 2816) {
    int q = b - 1280;
    int r0 = (q >> 5) << 5, c0 = (q & 31) << 5;
    int c = tid & 31, rr = tid >> 5;
#pragma unroll
    for (int i = 0; i < 4; ++i) {
      int r = rr + i * 8;
      tile[r * 33 + c] = W1[(size_t)(r0 + r) * 1024 + c0 + c];
    }
    __syncthreads();
#pragma unroll
    for (int i = 0; i < 4; ++i) {
      int r = rr + i * 8;
      w1t[(size_t)(c0 + r) * 1536 + r0 + c] = __float2bfloat16(tile[c * 33 + r]);
    }
  } else if (b < 3328) {
    cast4h(W2, w2b, (b - 2816) * 256);
  } else if (b < 3840) {
    int q = b - 3328; tr32h(W3, w3t, 512, 1024, q >> 5, q & 31);
  } else if (b < 4352) {
    cast4h(W4, w4b, (b - 3840) * 256);
  } else if (b < 4384) {
    int q = b - 4352; tr32h(Wc, wct, 512, 64, q >> 1, q & 1);
  } else if (b < 4388) {
    int c = (b - 4384) * 256 + tid;
    float s = 0.f;
#pragma unroll 32
    for (int j = 0; j < 512; ++j) s += b2[j] * W3[(size_t)j * 1024 + c];
    b23[c] = 512.f * s + b3[c];
  } else {
    if (tid < 64) {
      float s = 0.f;
#pragma unroll 32
      for (int j = 0; j < 512; ++j) s += b4[j] * Wc[(size_t)j * 64 + tid];
      bc4[tid] = s + bc[tid];
    }
  }
}

// ================= K1: pgemm — blocks 0..511: P-tile GEMM -> global P slabs (fp16,
// b1 folded into the j=2 table). Blocks 512..783: fused weight-product GEMMs.
// P slab layout per (t,win): [3][160] rows x 72 B (32 cols fp16 + 8 B pad) = 34560 B.
__global__ __launch_bounds__(256) void pgemm_wgemm(
    const __hip_bfloat16* __restrict__ xbf,   // [16][160][512]
    const __hip_bfloat16* __restrict__ w1t,   // [1024][1536]
    const float* __restrict__ b1,             // [1024]
    char* __restrict__ pbuf,                  // 512 slabs x 34560 B
    const _Float16* __restrict__ w3t,         // [1024][512]
    const _Float16* __restrict__ w2b,         // [1024][512]
    const _Float16* __restrict__ wct,         // [64][512]
    const _Float16* __restrict__ w4b,         // [1024][512]
    _Float16* __restrict__ w23t,              // [1024][1024]
    _Float16* __restrict__ w4ct)              // [64][1024]
{
  __shared__ __align__(16) char smem[34560];
  const int bx = blockIdx.x;
  const int tid = threadIdx.x;
  const int ln = tid & 63, wv = tid >> 6;
  const int col16 = ln & 15, quad = ln >> 4;

  if (bx >= 512) {
    // ---- weight GEMM: out[m][n] = sum_k A[m][k]*Bt[n][k], K=512 fp16, 64x64 tile
    const int b = bx - 512;
    const _Float16 *A, *Bt;
    _Float16* out;
    int m0, n0;
    if (b < 256) { A = w3t; Bt = w2b; out = w23t; m0 = (b >> 4) << 6; n0 = (b & 15) << 6; }
    else         { A = wct; Bt = w4b; out = w4ct; m0 = 0;             n0 = (b - 256) << 6; }
    char* Abuf = smem;              // 64 x 256B = 16384
    char* Bbuf = smem + 16384;      // 16384

    f32x4 acc[4];
#pragma unroll
    for (int a = 0; a < 4; ++a) acc[a] = (f32x4){0.f, 0.f, 0.f, 0.f};

#pragma unroll 1
    for (int kk = 0; kk < 512; kk += 128) {
      __syncthreads();
#pragma unroll
      for (int p = 0; p < 4; ++p) {           // A: 64 rows x 16 chunks
        int i = p * 256 + tid, r = i >> 4, q = i & 15;
        async16(A + (size_t)(m0 + r) * 512 + kk + ((q ^ (r & 7)) << 3), Abuf + (i << 4));
      }
#pragma unroll
      for (int p = 0; p < 4; ++p) {           // B: 64 rows x 16 chunks
        int i = p * 256 + tid, r = i >> 4, q = i & 15;
        async16(Bt + (size_t)(n0 + r) * 512 + kk + ((q ^ (r & 7)) << 3), Bbuf + (i << 4));
      }
      __syncthreads();

#pragma unroll
      for (int ks = 0; ks < 4; ++ks) {
        const int qq = (ks << 2) + quad;
        const int rn = (wv << 4) + col16;
        f16x8 bfm = *(const f16x8*)(Bbuf + rn * 256 + ((qq ^ (rn & 7)) << 4));
#pragma unroll
        for (int a = 0; a < 4; ++a) {
          int rm = (a << 4) + col16;
          f16x8 af = *(const f16x8*)(Abuf + rm * 256 + ((qq ^ (rm & 7)) << 4));
          acc[a] = __builtin_amdgcn_mfma_f32_16x16x32_f16(af, bfm, acc[a], 0, 0, 0);
        }
      }
    }

    const int n = n0 + (wv << 4) + col16;
#pragma unroll
    for (int a = 0; a < 4; ++a)
#pragma unroll
      for (int r = 0; r < 4; ++r) {
        size_t row = m0 + (a << 4) + (quad << 2) + r;
        out[row * 1024 + n] = (_Float16)acc[a][r];
      }
    return;
  }

  // ---------------- P-tile GEMM path ----------------
  char* Abuf  = smem;                      // [0, 20480)   phase 1
  char* Bbuf  = smem + 20480;              // [20480, 32768) phase 1
  char* Ptile = smem;                      // [0, 34560)   phase 2 (overlaps staging)

  const int t   = bx >> 5;
  const int nt  = bx & 31;
  const int n0  = nt << 5;                 // 32-col output window

  const int wr = wv >> 1, wc = wv & 1;     // 2x2 wave grid: 80 rows x 48 cols each

  const __hip_bfloat16* xt = xbf + (size_t)t * (SW_ * D_);

  int aoff[5], lofA[5];
#pragma unroll
  for (int s = 0; s < 5; ++s) {            // A: 160 rows x 8 chunks = 1280
    int i = s * 256 + tid, r = i >> 3, q = i & 7;
    aoff[s] = r * 512 + ((q ^ (r & 7)) << 3);
    lofA[s] = i << 4;
  }
  int boff[3], lofB[3];
#pragma unroll
  for (int s = 0; s < 3; ++s) {            // B: 96 rows (j*32+nc) x 8 chunks = 768
    int i = s * 256 + tid, r = i >> 3, q = i & 7;
    int nc = r & 31, j = r >> 5;
    boff[s] = (n0 + nc) * 1536 + j * 512 + ((q ^ (r & 7)) << 3);
    lofB[s] = i << 4;
  }

  f32x4 acc[5][3];
#pragma unroll
  for (int a = 0; a < 5; ++a)
#pragma unroll
    for (int b = 0; b < 3; ++b)
      acc[a][b] = (f32x4){0.f, 0.f, 0.f, 0.f};

  // ---- phase 1: K-loop
#pragma unroll 1
  for (int kk = 0; kk < 512; kk += 64) {
    __syncthreads();
#pragma unroll
    for (int s = 0; s < 5; ++s) async16(xt + aoff[s] + kk, Abuf + lofA[s]);
#pragma unroll
    for (int s = 0; s < 3; ++s) async16(w1t + boff[s] + kk, Bbuf + lofB[s]);
    __syncthreads();

#pragma unroll
    for (int ks = 0; ks < 2; ++ks) {
      const int qq = (ks << 2) + quad;
      bf16x8 af[5], bfr[3];
#pragma unroll
      for (int a = 0; a < 5; ++a) {
        int rm = wr * 80 + a * 16 + col16;
        af[a] = *(const bf16x8*)(Abuf + rm * 128 + ((qq ^ (rm & 7)) << 4));
      }
#pragma unroll
      for (int b = 0; b < 3; ++b) {
        int rn = wc * 48 + b * 16 + col16;
        bfr[b] = *(const bf16x8*)(Bbuf + rn * 128 + ((qq ^ (rn & 7)) << 4));
      }
#pragma unroll
      for (int a = 0; a < 5; ++a)
#pragma unroll
        for (int b = 0; b < 3; ++b)
          acc[a][b] = __builtin_amdgcn_mfma_f32_16x16x32_bf16(af[a], bfr[b], acc[a][b], 0, 0, 0);
    }
  }

  __syncthreads();   // all staging reads done; smem now becomes Ptile

  // ---- write P to LDS as fp16, layout [j][sw][nc] stride 72 B; fold b1 into j==2
#pragma unroll
  for (int b = 0; b < 3; ++b) {
    int c = wc * 48 + b * 16 + col16;       // 0..95; j constant per (wc,b) chunk
    int j = c >> 5, nc = c & 31;
    float bv = (j == 2) ? b1[n0 + nc] : 0.f;
#pragma unroll
    for (int a = 0; a < 5; ++a) {
      int mb = wr * 80 + a * 16 + quad * 4;
#pragma unroll
      for (int r = 0; r < 4; ++r)
        *(_Float16*)(Ptile + (j * 160 + mb + r) * 72 + nc * 2) =
            (_Float16)(acc[a][b][r] + bv);
    }
  }
  __syncthreads();

  // ---- coalesced LDS -> global slab copy (2160 x 16 B)
  char* gP = pbuf + (size_t)bx * 34560;
#pragma unroll
  for (int p = 0; p < 9; ++p) {
    int i = p * 256 + tid;
    if (i < 2160)
      *(uint4*)(gP + (size_t)i * 16) = *(const uint4*)(Ptile + i * 16);
  }
}

// ================= K2: gather — block = (t, win, w-pair). Stages P slab + 2 w's
// pre-scaled indices, then packed-fp16 gather/relu/reduce. 2560 blocks, 2 barriers.
__global__ __launch_bounds__(256) void gather_kernel(
    const char* __restrict__ pbuf,
    const int* __restrict__ tidx,             // [16][10][3][512]
    _Float16* __restrict__ Hsb)               // [160][1024] fp16
{
  __shared__ __align__(16) char P[34560];
  __shared__ int idx[2][1536];
  __shared__ float red[2][128];
  const int tid = threadIdx.x;
  const int wp  = blockIdx.x;               // 0..4 -> w = 2*wp, 2*wp+1
  const int win = blockIdx.y;               // 0..31
  const int t   = blockIdx.z;               // 0..15
  const int ln = tid & 63, wv = tid >> 6;

  // stage P slab (34560 B) via global_load_lds
  const char* ps = pbuf + (size_t)(t * 32 + win) * 34560;
#pragma unroll
  for (int p = 0; p < 9; ++p) {
    int i = p * 256 + tid;
    if (i < 2160) async16(ps + (size_t)i * 16, P + i * 16);
  }

  // stage both w's indices, pre-scaled by the 72-B row stride
  const int* isrc = tidx + (size_t)(t * 10 + wp * 2) * 1536;
#pragma unroll
  for (int v = 0; v < 2; ++v) {
    const int* s = isrc + v * 1536;
    int4 ra = *(const int4*)(s + (tid << 2));
    *(int4*)(&idx[v][tid << 2]) =
        make_int4(ra.x * 72, ra.y * 72, ra.z * 72, ra.w * 72);
    if (tid < 128) {
      int4 rb = *(const int4*)(s + 1024 + (tid << 2));
      *(int4*)(&idx[v][1024 + (tid << 2)]) =
          make_int4(rb.x * 72, rb.y * 72, rb.z * 72, rb.w * 72);
    }
  }
  __syncthreads();                          // barrier drains vmcnt + lgkm

  const int nq = tid & 7;                   // 4 cols: nc = nq*4..+3
  const int kq = tid >> 3;                  // 0..31, k in [kq*16, kq*16+16)
  const char* Pt0 = P + (nq << 3);
  const char* Pt1 = Pt0 + 11520;
  const char* Pt2 = Pt0 + 23040;

#pragma unroll
  for (int v = 0; v < 2; ++v) {
    const int* cid = idx[v];
    h2v acc01 = (h2v)0, acc23 = (h2v)0;
#pragma unroll
    for (int u = 0; u < 4; ++u) {
      const int kb = (kq << 4) + (u << 2);
      int4 i0 = *(const int4*)(cid + kb);
      int4 i1 = *(const int4*)(cid + 512 + kb);
      int4 i2 = *(const int4*)(cid + 1024 + kb);
#define STEP(IA, IB, IC)                                                  \
      {                                                                   \
        uint2 p0 = *(const uint2*)(Pt0 + (IA));                           \
        uint2 p1 = *(const uint2*)(Pt1 + (IB));                           \
        uint2 p2 = *(const uint2*)(Pt2 + (IC));                           \
        h2v sx = bc2(p0.x) + bc2(p1.x) + bc2(p2.x);                       \
        h2v sy = bc2(p0.y) + bc2(p1.y) + bc2(p2.y);                       \
        acc01 += relu2(sx);                                               \
        acc23 += relu2(sy);                                               \
      }
      STEP(i0.x, i1.x, i2.x)
      STEP(i0.y, i1.y, i2.y)
      STEP(i0.z, i1.z, i2.z)
      STEP(i0.w, i1.w, i2.w)
#undef STEP
    }

    f32x4 a4 = (f32x4){(float)acc01.x, (float)acc01.y,
                       (float)acc23.x, (float)acc23.y};
    // reduce over kq (lane bits 3..5), then across waves via LDS
#pragma unroll
    for (int off = 8; off <= 32; off <<= 1) {
      a4.x += __shfl_xor(a4.x, off);
      a4.y += __shfl_xor(a4.y, off);
      a4.z += __shfl_xor(a4.z, off);
      a4.w += __shfl_xor(a4.w, off);
    }
    if ((ln >> 3) == 0)
      *(f32x4*)(&red[v][wv * 32 + (nq << 2)]) = a4;
  }
  __syncthreads();
  if (tid < 64) {
    int v = tid >> 5, c = tid & 31;
    float s = red[v][c] + red[v][32 + c] + red[v][64 + c] + red[v][96 + c];
    Hsb[(size_t)(t * 10 + wp * 2 + v) * N1_ + (win << 5) + c] = (_Float16)s;
  }
}

// ================= K3: mid_gemm — u = relu(Hs @ W23 + b23), fp16 in/out, K=1024.
__global__ __launch_bounds__(256) void mid_gemm(
    const _Float16* __restrict__ A,          // [160][1024]
    const _Float16* __restrict__ Bt,         // [1024][1024]
    const float* __restrict__ bias,
    _Float16* __restrict__ out)              // [160][1024]
{
  __shared__ __align__(16) char Abuf[40960];  // 80 rows x 512 B
  __shared__ __align__(16) char Bbuf[32768];  // 64 rows x 512 B
  const int tid = threadIdx.x;
  const int n0 = blockIdx.x << 6;
  const int m0 = blockIdx.y * 80;
  const int ln = tid & 63, wv = tid >> 6;
  const int col16 = ln & 15, quad = ln >> 4;

  f32x4 acc[5];
#pragma unroll
  for (int a = 0; a < 5; ++a) acc[a] = (f32x4){0.f, 0.f, 0.f, 0.f};

#pragma unroll 1
  for (int kk = 0; kk < 1024; kk += 256) {
    __syncthreads();
#pragma unroll
    for (int p = 0; p < 10; ++p) {          // A: 80 rows x 32 chunks
      int i = p * 256 + tid, r = i >> 5, q = i & 31;
      async16(A + (size_t)(m0 + r) * 1024 + kk + ((q ^ (r & 7)) << 3), Abuf + (i << 4));
    }
#pragma unroll
    for (int p = 0; p < 8; ++p) {           // B: 64 rows x 32 chunks
      int i = p * 256 + tid, r = i >> 5, q = i & 31;
      async16(Bt + (size_t)(n0 + r) * 1024 + kk + ((q ^ (r & 7)) << 3), Bbuf + (i << 4));
    }
    __syncthreads();

#pragma unroll
    for (int ks = 0; ks < 8; ++ks) {
      const int qq = (ks << 2) + quad;
      const int rn = (wv << 4) + col16;
      f16x8 bfm = *(const f16x8*)(Bbuf + rn * 512 + ((qq ^ (rn & 7)) << 4));
#pragma unroll
      for (int a = 0; a < 5; ++a) {
        int rm = (a << 4) + col16;
        f16x8 af = *(const f16x8*)(Abuf + rm * 512 + ((qq ^ (rm & 7)) << 4));
        acc[a] = __builtin_amdgcn_mfma_f32_16x16x32_f16(af, bfm, acc[a], 0, 0, 0);
      }
    }
  }

  const int n = n0 + (wv << 4) + col16;
  const float bb = bias[n];
#pragma unroll
  for (int a = 0; a < 5; ++a)
#pragma unroll
    for (int r = 0; r < 4; ++r) {
      float v = fmaxf(acc[a][r] + bb, 0.f);
      out[(size_t)(m0 + (a << 4) + (quad << 2) + r) * 1024 + n] = (_Float16)v;
    }
}

// ================= K4: head — score = u @ W4c + bc4, softmax over 64. fp16 in, K=1024.
__global__ __launch_bounds__(256) void head_gemm2(
    const _Float16* __restrict__ A,          // [160][1024]
    const _Float16* __restrict__ Bt,         // [64][1024]
    const float* __restrict__ bc4,
    float* __restrict__ out)                 // [160][64]
{
  __shared__ __align__(16) char Abuf[40960];
  __shared__ __align__(16) char Bbuf[32768];
  __shared__ float sc[80 * 64];
  __shared__ float rs[80];
  const int tid = threadIdx.x;
  const int m0 = blockIdx.x * 80;
  const int ln = tid & 63, wv = tid >> 6;
  const int col16 = ln & 15, quad = ln >> 4;

  f32x4 acc[5];
#pragma unroll
  for (int a = 0; a < 5; ++a) acc[a] = (f32x4){0.f, 0.f, 0.f, 0.f};

#pragma unroll 1
  for (int kk = 0; kk < 1024; kk += 256) {
    __syncthreads();
#pragma unroll
    for (int p = 0; p < 10; ++p) {
      int i = p * 256 + tid, r = i >> 5, q = i & 31;
      async16(A + (size_t)(m0 + r) * 1024 + kk + ((q ^ (r & 7)) << 3), Abuf + (i << 4));
    }
#pragma unroll
    for (int p = 0; p < 8; ++p) {
      int i = p * 256 + tid, r = i >> 5, q = i & 31;
      async16(Bt + (size_t)r * 1024 + kk + ((q ^ (r & 7)) << 3), Bbuf + (i << 4));
    }
    __syncthreads();

#pragma unroll
    for (int ks = 0; ks < 8; ++ks) {
      const int qq = (ks << 2) + quad;
      const int rn = (wv << 4) + col16;
      f16x8 bfm = *(const f16x8*)(Bbuf + rn * 512 + ((qq ^ (rn & 7)) << 4));
#pragma unroll
      for (int a = 0; a < 5; ++a) {
        int rm = (a << 4) + col16;
        f16x8 af = *(const f16x8*)(Abuf + rm * 512 + ((qq ^ (rm & 7)) << 4));
        acc[a] = __builtin_amdgcn_mfma_f32_16x16x32_f16(af, bfm, acc[a], 0, 0, 0);
      }
    }
  }

  const int n = (wv << 4) + col16;
  const float bb = bc4[n];
#pragma unroll
  for (int a = 0; a < 5; ++a)
#pragma unroll
    for (int r = 0; r < 4; ++r)
      sc[((a << 4) + (quad << 2) + r) * 64 + n] = acc[a][r] + bb;
  __syncthreads();

  if (tid < 80) {
    float m = -1e30f;
    for (int c = 0; c < 64; ++c) m = fmaxf(m, sc[tid * 64 + c]);
    float s = 0.f;
    for (int c = 0; c < 64; ++c) {
      float e = expf(sc[tid * 64 + c] - m);
      sc[tid * 64 + c] = e;
      s += e;
    }
    rs[tid] = 1.f / s;
  }
  __syncthreads();
#pragma unroll
  for (int p = 0; p < 20; ++p) {
    int f = p * 256 + tid, r = f >> 6, c = f & 63;
    out[(size_t)(m0 + r) * 64 + c] = sc[f] * rs[r];
  }
}

extern "C" void kernel_launch(void* const* d_in, const int* in_sizes, int n_in,
                              void* d_out, int out_size, void* d_ws, size_t ws_size,
                              hipStream_t stream) {
  const float* x_in = (const float*)d_in[0];
  const int*   tidx = (const int*)d_in[1];
  const float* W1 = (const float*)d_in[2];
  const float* b1 = (const float*)d_in[3];
  const float* W2 = (const float*)d_in[4];
  const float* b2 = (const float*)d_in[5];
  const float* W3 = (const float*)d_in[6];
  const float* b3 = (const float*)d_in[7];
  const float* W4 = (const float*)d_in[8];
  const float* b4 = (const float*)d_in[9];
  const float* Wc = (const float*)d_in[10];
  const float* bc = (const float*)d_in[11];
  float* out = (float*)d_out;
  (void)in_sizes; (void)n_in; (void)out_size; (void)ws_size;

  char* ws = (char*)d_ws;
  __hip_bfloat16* xbf  = (__hip_bfloat16*)(ws + 0);         // 2,621,440
  __hip_bfloat16* w1t  = (__hip_bfloat16*)(ws + 2621440);   // 3,145,728 -> 5,767,168
  _Float16*       w2b  = (_Float16*)      (ws + 5767168);   // [1024][512] 1,048,576
  _Float16*       w3t  = (_Float16*)      (ws + 6815744);   // [1024][512] 1,048,576
  _Float16*       w4b  = (_Float16*)      (ws + 7864320);   // [1024][512] 1,048,576
  _Float16*       wct  = (_Float16*)      (ws + 8912896);   // [64][512]      65,536
  float*          b23  = (float*)         (ws + 8978432);   // [1024]          4,096
  float*          bc4  = (float*)         (ws + 8982528);   // [64]              256
  _Float16*       Hsb  = (_Float16*)      (ws + 8982784);   // [160][1024]   327,680
  _Float16*       w23t = (_Float16*)      (ws + 9310464);   // [1024][1024] 2,097,152
  _Float16*       w4ct = (_Float16*)      (ws + 11407616);  // [64][1024]    131,072
  char*           pbuf = ws + 11538688;                     // 512*34560 = 17,694,720
  _Float16*       ub   = (_Float16*)      (ws + 11538688);  // overlays pbuf (pbuf dead
                                                            // before mid_gemm writes ub)

  // K0: all casts/transposes + bias folds (one launch)
  prep_all<<<4389, 256, 0, stream>>>(x_in, W1, W2, W3, W4, Wc, b2, b3, b4, bc,
                                     xbf, w1t, w2b, w3t, w4b, wct, b23, bc4);

  // K1: P-tile GEMMs (512 blocks) + overlapped weight-product GEMMs (272 blocks)
  pgemm_wgemm<<<784, 256, 0, stream>>>(xbf, w1t, b1, pbuf,
                                       w3t, w2b, wct, w4b, w23t, w4ct);

  // K2: gather/relu/reduce — 16t x 32win x 5 w-pairs = 2560 blocks
  gather_kernel<<<dim3(5, 32, 16), 256, 0, stream>>>(pbuf, tidx, Hsb);

  // K3: u = relu(Hs @ W23 + b23)
  mid_gemm<<<dim3(16, 2), 256, 0, stream>>>(Hsb, w23t, b23, ub);

  // K4: softmax(u @ W4c + bc4)
  head_gemm2<<<2, 256, 0, stream>>>(ub, w4ct, bc4, out);
}

// Round 4
// 146.710 us; speedup vs baseline: 1.0955x; 1.0955x over previous
//
#include <hip/hip_runtime.h>
#include <hip/hip_bf16.h>

// Problem constants (T,S,W,D,C,K) = (16,16,10,512,64,512)
#define T_  16
#define W_  10
#define D_  512
#define SW_ 160      // S*W
#define N1_ 1024     // 2*D
#define KT_ 512      // triplets per (t,w)

typedef __bf16 bf16x8 __attribute__((ext_vector_type(8)));
typedef _Float16 f16x8 __attribute__((ext_vector_type(8)));
typedef _Float16 h2v  __attribute__((ext_vector_type(2)));
typedef float  f32x4  __attribute__((ext_vector_type(4)));

// async global->LDS, 16B per lane (global addr per-lane; LDS dest = wave base + lane*16)
__device__ __forceinline__ void async16(const void* g, void* l) {
  __builtin_amdgcn_global_load_lds(
      (__attribute__((address_space(1))) void*)(g),
      (__attribute__((address_space(3))) void*)(l), 16, 0, 0);
}

__device__ __forceinline__ h2v bc2(unsigned u) { return __builtin_bit_cast(h2v, u); }
// relu on packed fp16 pair (v_pk_max_f16 with inline 0)
__device__ __forceinline__ h2v relu2(h2v a) {
  h2v r;
  asm("v_pk_max_f16 %0, %1, 0" : "=v"(r) : "v"(a));
  return r;
}

// ================= K0: prep_all — every cast/transpose/bias-fold in ONE launch
__global__ __launch_bounds__(256) void prep_all(
    const float* __restrict__ x_in, const float* __restrict__ W1,
    const float* __restrict__ W2, const float* __restrict__ W3,
    const float* __restrict__ W4, const float* __restrict__ Wc,
    const float* __restrict__ b2, const float* __restrict__ b3,
    const float* __restrict__ b4, const float* __restrict__ bc,
    __hip_bfloat16* __restrict__ xbf, __hip_bfloat16* __restrict__ w1t,
    _Float16* __restrict__ w2b, _Float16* __restrict__ w3t,
    _Float16* __restrict__ w4b, _Float16* __restrict__ wct,
    float* __restrict__ b23, float* __restrict__ bc4)
{
  __shared__ float tile[32 * 33];
  const int b = blockIdx.x, tid = threadIdx.x;

  auto cast4h = [&](const float* src, _Float16* dst, int base) {
    int i = (base + tid) << 2;
    float4 v = *(const float4*)(src + i);
    __align__(8) _Float16 o4[4] = {(_Float16)v.x, (_Float16)v.y,
                                   (_Float16)v.z, (_Float16)v.w};
    *(uint2*)(dst + i) = *(const uint2*)o4;
  };
  auto tr32h = [&](const float* src, _Float16* dst, int R, int C, int rt, int ct) {
    int r0 = rt << 5, c0 = ct << 5;
    int c = tid & 31, rr = tid >> 5;
#pragma unroll
    for (int i = 0; i < 4; ++i) {
      int r = rr + i * 8;
      tile[r * 33 + c] = src[(size_t)(r0 + r) * C + c0 + c];
    }
    __syncthreads();
#pragma unroll
    for (int i = 0; i < 4; ++i) {
      int r = rr + i * 8;
      dst[(size_t)(c0 + r) * R + r0 + c] = (_Float16)tile[c * 33 + r];
    }
  };

  if (b < 1280) {
    int i = (b * 256 + tid) << 2;
    float4 v = *(const float4*)(x_in + i);
    __align__(8) __hip_bfloat16 o4[4];
    o4[0] = __float2bfloat16(v.x); o4[1] = __float2bfloat16(v.y);
    o4[2] = __float2bfloat16(v.z); o4[3] = __float2bfloat16(v.w);
    *(uint2*)(xbf + i) = *(const uint2*)o4;
  } else if (b < 2816) {
    int q = b - 1280;
    int r0 = (q >> 5) << 5, c0 = (q & 31) << 5;
    int c = tid & 31, rr = tid >> 5;
#pragma unroll
    for (int i = 0; i < 4; ++i) {
      int r = rr + i * 8;
      tile[r * 33 + c] = W1[(size_t)(r0 + r) * 1024 + c0 + c];
    }
    __syncthreads();
#pragma unroll
    for (int i = 0; i < 4; ++i) {
      int r = rr + i * 8;
      w1t[(size_t)(c0 + r) * 1536 + r0 + c] = __float2bfloat16(tile[c * 33 + r]);
    }
  } else if (b < 3328) {
    cast4h(W2, w2b, (b - 2816) * 256);
  } else if (b < 3840) {
    int q = b - 3328; tr32h(W3, w3t, 512, 1024, q >> 5, q & 31);
  } else if (b < 4352) {
    cast4h(W4, w4b, (b - 3840) * 256);
  } else if (b < 4384) {
    int q = b - 4352; tr32h(Wc, wct, 512, 64, q >> 1, q & 1);
  } else if (b < 4388) {
    int c = (b - 4384) * 256 + tid;
    float s = 0.f;
#pragma unroll 32
    for (int j = 0; j < 512; ++j) s += b2[j] * W3[(size_t)j * 1024 + c];
    b23[c] = 512.f * s + b3[c];
  } else {
    if (tid < 64) {
      float s = 0.f;
#pragma unroll 32
      for (int j = 0; j < 512; ++j) s += b4[j] * Wc[(size_t)j * 64 + tid];
      bc4[tid] = s + bc[tid];
    }
  }
}

// ================= K1: group blocks 0..511 (BK=128 GEMM + paired-w gather)
//               + fused weight-product GEMM blocks 512..783
__global__ __launch_bounds__(256) void group_wgemm(
    const __hip_bfloat16* __restrict__ xbf,   // [16][160][512]
    const __hip_bfloat16* __restrict__ w1t,   // [1024][1536]
    const int* __restrict__ tidx,             // [16][10][3][512]
    const float* __restrict__ b1,             // [1024]
    _Float16* __restrict__ Hsb,               // [160][1024] fp16
    const _Float16* __restrict__ w3t,         // [1024][512]
    const _Float16* __restrict__ w2b,         // [1024][512]
    const _Float16* __restrict__ wct,         // [64][512]
    const _Float16* __restrict__ w4b,         // [1024][512]
    _Float16* __restrict__ w23t,              // [1024][1024]
    _Float16* __restrict__ w4ct)              // [64][1024]
{
  __shared__ __align__(16) char smem[65536];
  const int bx = blockIdx.x;
  const int tid = threadIdx.x;
  const int ln = tid & 63, wv = tid >> 6;
  const int col16 = ln & 15, quad = ln >> 4;

  if (bx >= 512) {
    // ---- weight GEMM: out[m][n] = sum_k A[m][k]*Bt[n][k], K=512 fp16, 64x64 tile
    const int b = bx - 512;
    const _Float16 *A, *Bt;
    _Float16* out;
    int m0, n0;
    if (b < 256) { A = w3t; Bt = w2b; out = w23t; m0 = (b >> 4) << 6; n0 = (b & 15) << 6; }
    else         { A = wct; Bt = w4b; out = w4ct; m0 = 0;             n0 = (b - 256) << 6; }
    char* Abuf = smem;              // 64 x 256B = 16384
    char* Bbuf = smem + 16384;      // 16384

    f32x4 acc[4];
#pragma unroll
    for (int a = 0; a < 4; ++a) acc[a] = (f32x4){0.f, 0.f, 0.f, 0.f};

#pragma unroll 1
    for (int kk = 0; kk < 512; kk += 128) {
      __syncthreads();
#pragma unroll
      for (int p = 0; p < 4; ++p) {           // A: 64 rows x 16 chunks
        int i = p * 256 + tid, r = i >> 4, q = i & 15;
        async16(A + (size_t)(m0 + r) * 512 + kk + ((q ^ (r & 7)) << 3), Abuf + (i << 4));
      }
#pragma unroll
      for (int p = 0; p < 4; ++p) {           // B: 64 rows x 16 chunks
        int i = p * 256 + tid, r = i >> 4, q = i & 15;
        async16(Bt + (size_t)(n0 + r) * 512 + kk + ((q ^ (r & 7)) << 3), Bbuf + (i << 4));
      }
      __syncthreads();

#pragma unroll
      for (int ks = 0; ks < 4; ++ks) {
        const int qq = (ks << 2) + quad;
        const int rn = (wv << 4) + col16;
        f16x8 bfm = *(const f16x8*)(Bbuf + rn * 256 + ((qq ^ (rn & 7)) << 4));
#pragma unroll
        for (int a = 0; a < 4; ++a) {
          int rm = (a << 4) + col16;
          f16x8 af = *(const f16x8*)(Abuf + rm * 256 + ((qq ^ (rm & 7)) << 4));
          acc[a] = __builtin_amdgcn_mfma_f32_16x16x32_f16(af, bfm, acc[a], 0, 0, 0);
        }
      }
    }

    const int n = n0 + (wv << 4) + col16;
#pragma unroll
    for (int a = 0; a < 4; ++a)
#pragma unroll
      for (int r = 0; r < 4; ++r) {
        size_t row = m0 + (a << 4) + (quad << 2) + r;
        out[row * 1024 + n] = (_Float16)acc[a][r];
      }
    return;
  }

  // ---------------- group part ----------------
  char* Abuf  = smem;                      // [0, 40960)  phase 1 (BK=128, 160x256B)
  char* Bbuf  = smem + 40960;              // [40960, 65536) phase 1 (96x256B)
  char* Ptile = smem;                      // [0, 34560)  phase 2
  int*  ibuf  = (int*)(smem + 34560);      // 4 x 1536 ints = 24576 B
  float* red  = (float*)(smem + 59136);    // 2 x 128 floats = 1024 B

  const int t   = bx >> 5;
  const int nt  = bx & 31;
  const int n0  = nt << 5;                 // 32-col output window

  const int wr = wv >> 1, wc = wv & 1;     // 2x2 wave grid: 80 rows x 48 cols each

  const __hip_bfloat16* xt = xbf + (size_t)t * (SW_ * D_);

  int aoff[10], lofA[10];
#pragma unroll
  for (int s = 0; s < 10; ++s) {           // A: 160 rows x 16 chunks = 2560
    int i = s * 256 + tid, r = i >> 4, q = i & 15;
    aoff[s] = r * 512 + ((q ^ (r & 7)) << 3);
    lofA[s] = i << 4;
  }
  int boff[6], lofB[6];
#pragma unroll
  for (int s = 0; s < 6; ++s) {            // B: 96 rows (j*32+nc) x 16 chunks = 1536
    int i = s * 256 + tid, r = i >> 4, q = i & 15;
    int nc = r & 31, j = r >> 5;
    boff[s] = (n0 + nc) * 1536 + j * 512 + ((q ^ (r & 7)) << 3);
    lofB[s] = i << 4;
  }

  f32x4 acc[5][3];
#pragma unroll
  for (int a = 0; a < 5; ++a)
#pragma unroll
    for (int b = 0; b < 3; ++b)
      acc[a][b] = (f32x4){0.f, 0.f, 0.f, 0.f};

  // ---- phase 1: K-loop, BK=128 (4 iters)
#pragma unroll 1
  for (int kk = 0; kk < 512; kk += 128) {
    __syncthreads();
#pragma unroll
    for (int s = 0; s < 10; ++s) async16(xt + aoff[s] + kk, Abuf + lofA[s]);
#pragma unroll
    for (int s = 0; s < 6; ++s) async16(w1t + boff[s] + kk, Bbuf + lofB[s]);
    __syncthreads();

#pragma unroll
    for (int ks = 0; ks < 4; ++ks) {
      const int qq = (ks << 2) + quad;
      bf16x8 af[5], bfr[3];
#pragma unroll
      for (int a = 0; a < 5; ++a) {
        int rm = wr * 80 + a * 16 + col16;
        af[a] = *(const bf16x8*)(Abuf + rm * 256 + ((qq ^ (rm & 7)) << 4));
      }
#pragma unroll
      for (int b = 0; b < 3; ++b) {
        int rn = wc * 48 + b * 16 + col16;
        bfr[b] = *(const bf16x8*)(Bbuf + rn * 256 + ((qq ^ (rn & 7)) << 4));
      }
#pragma unroll
      for (int a = 0; a < 5; ++a)
#pragma unroll
        for (int b = 0; b < 3; ++b)
          acc[a][b] = __builtin_amdgcn_mfma_f32_16x16x32_bf16(af[a], bfr[b], acc[a][b], 0, 0, 0);
    }
  }

  __syncthreads();   // all staging reads done; smem now becomes Ptile/ibuf

  // ---- write P to LDS as fp16, layout [j][sw][nc] stride 72 B; fold b1 into j==2
#pragma unroll
  for (int b = 0; b < 3; ++b) {
    int c = wc * 48 + b * 16 + col16;       // 0..95; j constant per (wc,b) chunk
    int j = c >> 5, nc = c & 31;
    float bv = (j == 2) ? b1[n0 + nc] : 0.f;
#pragma unroll
    for (int a = 0; a < 5; ++a) {
      int mb = wr * 80 + a * 16 + quad * 4;
#pragma unroll
      for (int r = 0; r < 4; ++r)
        *(_Float16*)(Ptile + (j * 160 + mb + r) * 72 + nc * 2) =
            (_Float16)(acc[a][b][r] + bv);
    }
  }

  // ---- phase 2: paired-w gather + relu + reduce (5 iterations)
  const int nq = tid & 7;                   // 4 cols: nc = nq*4..+3
  const int kq = tid >> 3;                  // 0..31, k in [kq*16, kq*16+16)
  const char* Pt0 = Ptile + (nq << 3);
  const char* Pt1 = Pt0 + 11520;
  const char* Pt2 = Pt0 + 23040;

  const int* tsrc = tidx + (size_t)t * 10 * 1536;
  int4 ra[2], rb[2];
  auto sst2 = [&](int* dstbase) {           // scale by 72-B row stride, store pair
#pragma unroll
    for (int v = 0; v < 2; ++v) {
      int* dst = dstbase + v * 1536;
      *(int4*)(dst + (tid << 2)) =
          make_int4(ra[v].x * 72, ra[v].y * 72, ra[v].z * 72, ra[v].w * 72);
      if (tid < 128)
        *(int4*)(dst + 1024 + (tid << 2)) =
            make_int4(rb[v].x * 72, rb[v].y * 72, rb[v].z * 72, rb[v].w * 72);
    }
  };

  // prologue: stage pair 0
#pragma unroll
  for (int v = 0; v < 2; ++v) {
    const int* s0 = tsrc + v * 1536;
    ra[v] = *(const int4*)(s0 + (tid << 2));
    if (tid < 128) rb[v] = *(const int4*)(s0 + 1024 + (tid << 2));
  }
  sst2(ibuf);
  int cur = 0;

#pragma unroll 1
  for (int wp = 0; wp < 5; ++wp) {
    __syncthreads();       // cur idx + Ptile visible; red consumed
    if (wp < 4) {          // prefetch next pair's idx into regs
#pragma unroll
      for (int v = 0; v < 2; ++v) {
        const int* s2 = tsrc + (wp * 2 + 2 + v) * 1536;
        ra[v] = *(const int4*)(s2 + (tid << 2));
        if (tid < 128) rb[v] = *(const int4*)(s2 + 1024 + (tid << 2));
      }
    }

    const int* cb = ibuf + cur * 3072;
    f32x4 a4[2];
#pragma unroll
    for (int v = 0; v < 2; ++v) {
      const int* cid = cb + v * 1536;
      h2v acc01 = (h2v)0, acc23 = (h2v)0;
#pragma unroll
      for (int u = 0; u < 4; ++u) {
        const int kb = (kq << 4) + (u << 2);
        int4 i0 = *(const int4*)(cid + kb);
        int4 i1 = *(const int4*)(cid + 512 + kb);
        int4 i2 = *(const int4*)(cid + 1024 + kb);
#define STEP(IA, IB, IC)                                                  \
        {                                                                 \
          uint2 p0 = *(const uint2*)(Pt0 + (IA));                         \
          uint2 p1 = *(const uint2*)(Pt1 + (IB));                         \
          uint2 p2 = *(const uint2*)(Pt2 + (IC));                         \
          h2v sx = bc2(p0.x) + bc2(p1.x) + bc2(p2.x);                     \
          h2v sy = bc2(p0.y) + bc2(p1.y) + bc2(p2.y);                     \
          acc01 += relu2(sx);                                             \
          acc23 += relu2(sy);                                             \
        }
        STEP(i0.x, i1.x, i2.x)
        STEP(i0.y, i1.y, i2.y)
        STEP(i0.z, i1.z, i2.z)
        STEP(i0.w, i1.w, i2.w)
#undef STEP
      }
      a4[v] = (f32x4){(float)acc01.x, (float)acc01.y,
                      (float)acc23.x, (float)acc23.y};
    }

    if (wp < 4) sst2(ibuf + (cur ^ 1) * 3072);   // store next pair's idx

    // reduce over kq (lane bits 3..5), then across waves via LDS
#pragma unroll
    for (int v = 0; v < 2; ++v) {
#pragma unroll
      for (int off = 8; off <= 32; off <<= 1) {
        a4[v].x += __shfl_xor(a4[v].x, off);
        a4[v].y += __shfl_xor(a4[v].y, off);
        a4[v].z += __shfl_xor(a4[v].z, off);
        a4[v].w += __shfl_xor(a4[v].w, off);
      }
      if ((ln >> 3) == 0)
        *(f32x4*)(red + v * 128 + wv * 32 + (nq << 2)) = a4[v];
    }
    __syncthreads();       // red ready; next-pair idx committed
    if (tid < 64) {
      int v = tid >> 5, c = tid & 31;
      const float* rv = red + v * 128;
      float s = rv[c] + rv[32 + c] + rv[64 + c] + rv[96 + c];
      Hsb[(size_t)(t * 10 + wp * 2 + v) * N1_ + n0 + c] = (_Float16)s;
    }
    cur ^= 1;
  }
}

// ================= K2: mid_head — u = relu(Hs@W23 + b23) (kept in LDS only),
// then partial head: psc[nblk][160][64] = u_tile @ W4c_slice^T. Grid (16,2).
__global__ __launch_bounds__(256) void mid_head(
    const _Float16* __restrict__ A,          // Hsb [160][1024]
    const _Float16* __restrict__ Bt,         // w23t [1024][1024]
    const _Float16* __restrict__ W4c,        // w4ct [64][1024]
    const float* __restrict__ bias,          // b23
    float* __restrict__ psc)                 // [16][160][64] f32
{
  __shared__ __align__(16) char Abuf[40960];  // 80 rows x 512 B
  __shared__ __align__(16) char Bbuf[32768];  // 64 rows x 512 B
  __shared__ __align__(16) char Hbuf[8192];   // W4c slice: 64 rows x 128 B
  const int tid = threadIdx.x;
  const int n0 = blockIdx.x << 6;
  const int m0 = blockIdx.y * 80;
  const int ln = tid & 63, wv = tid >> 6;
  const int col16 = ln & 15, quad = ln >> 4;

  // stage the W4c slice early (drained by first K-loop barrier, free overlap)
#pragma unroll
  for (int p = 0; p < 2; ++p) {             // 64 rows x 8 chunks = 512
    int i = p * 256 + tid, r = i >> 3, q = i & 7;
    async16(W4c + (size_t)r * 1024 + n0 + ((q ^ (r & 7)) << 3), Hbuf + (i << 4));
  }

  f32x4 acc[5];
#pragma unroll
  for (int a = 0; a < 5; ++a) acc[a] = (f32x4){0.f, 0.f, 0.f, 0.f};

#pragma unroll 1
  for (int kk = 0; kk < 1024; kk += 256) {
    __syncthreads();
#pragma unroll
    for (int p = 0; p < 10; ++p) {          // A: 80 rows x 32 chunks
      int i = p * 256 + tid, r = i >> 5, q = i & 31;
      async16(A + (size_t)(m0 + r) * 1024 + kk + ((q ^ (r & 7)) << 3), Abuf + (i << 4));
    }
#pragma unroll
    for (int p = 0; p < 8; ++p) {           // B: 64 rows x 32 chunks
      int i = p * 256 + tid, r = i >> 5, q = i & 31;
      async16(Bt + (size_t)(n0 + r) * 1024 + kk + ((q ^ (r & 7)) << 3), Bbuf + (i << 4));
    }
    __syncthreads();

#pragma unroll
    for (int ks = 0; ks < 8; ++ks) {
      const int qq = (ks << 2) + quad;
      const int rn = (wv << 4) + col16;
      f16x8 bfm = *(const f16x8*)(Bbuf + rn * 512 + ((qq ^ (rn & 7)) << 4));
#pragma unroll
      for (int a = 0; a < 5; ++a) {
        int rm = (a << 4) + col16;
        f16x8 af = *(const f16x8*)(Abuf + rm * 512 + ((qq ^ (rm & 7)) << 4));
        acc[a] = __builtin_amdgcn_mfma_f32_16x16x32_f16(af, bfm, acc[a], 0, 0, 0);
      }
    }
  }

  // ---- u tile -> LDS (fp16, 80 rows x 128 B, chunk-swizzled); no global write
  const float bb = bias[n0 + (wv << 4) + col16];
  __syncthreads();                          // all Abuf/Bbuf reads done
  char* U = Abuf;                           // overlay
  const int cl = (wv << 4) + col16;         // local col 0..63
#pragma unroll
  for (int a = 0; a < 5; ++a)
#pragma unroll
    for (int r = 0; r < 4; ++r) {
      float v = fmaxf(acc[a][r] + bb, 0.f);
      int m = (a << 4) + (quad << 2) + r;
      *(_Float16*)(U + m * 128 + (((cl >> 3) ^ (m & 7)) << 4) + ((cl & 7) << 1)) =
          (_Float16)v;
    }
  __syncthreads();

  // ---- head partial: 80x64 u-tile @ 64x64 W4c-slice^T (K=64 -> 2 MFMA steps)
  f32x4 acc2[5];
#pragma unroll
  for (int a = 0; a < 5; ++a) acc2[a] = (f32x4){0.f, 0.f, 0.f, 0.f};
#pragma unroll
  for (int ks = 0; ks < 2; ++ks) {
    const int qq = (ks << 2) + quad;
    const int rn = (wv << 4) + col16;
    f16x8 bfm = *(const f16x8*)(Hbuf + rn * 128 + ((qq ^ (rn & 7)) << 4));
#pragma unroll
    for (int a = 0; a < 5; ++a) {
      int rm = (a << 4) + col16;
      f16x8 af = *(const f16x8*)(U + rm * 128 + ((qq ^ (rm & 7)) << 4));
      acc2[a] = __builtin_amdgcn_mfma_f32_16x16x32_f16(af, bfm, acc2[a], 0, 0, 0);
    }
  }
  float* po = psc + ((size_t)blockIdx.x * 160 + m0) * 64;
#pragma unroll
  for (int a = 0; a < 5; ++a)
#pragma unroll
    for (int r = 0; r < 4; ++r)
      po[((a << 4) + (quad << 2) + r) * 64 + (wv << 4) + col16] = acc2[a][r];
}

// ================= K3: softmax over 16-way partial sums. Grid 2: 80 rows/block.
__global__ __launch_bounds__(256) void softmax2(
    const float* __restrict__ psc,           // [16][160][64]
    const float* __restrict__ bc4,
    float* __restrict__ out)                 // [160][64]
{
  __shared__ float sc[80 * 64];
  __shared__ float rs[80];
  const int tid = threadIdx.x;
  const int m0 = blockIdx.x * 80;

#pragma unroll
  for (int p = 0; p < 5; ++p) {
    int f = p * 256 + tid;                   // 1280 = 80 rows x 16 col-groups
    int r = f >> 4, cq = f & 15;
    f32x4 s = (f32x4){0.f, 0.f, 0.f, 0.f};
#pragma unroll
    for (int j = 0; j < 16; ++j)
      s += *(const f32x4*)(psc + ((size_t)(j * 160) + m0 + r) * 64 + (cq << 2));
    s += *(const f32x4*)(bc4 + (cq << 2));
    *(f32x4*)(sc + r * 64 + (cq << 2)) = s;
  }
  __syncthreads();

  if (tid < 80) {
    float m = -1e30f;
    for (int c = 0; c < 64; ++c) m = fmaxf(m, sc[tid * 64 + c]);
    float s = 0.f;
    for (int c = 0; c < 64; ++c) {
      float e = expf(sc[tid * 64 + c] - m);
      sc[tid * 64 + c] = e;
      s += e;
    }
    rs[tid] = 1.f / s;
  }
  __syncthreads();
#pragma unroll
  for (int p = 0; p < 20; ++p) {
    int f = p * 256 + tid, r = f >> 6, c = f & 63;
    out[(size_t)(m0 + r) * 64 + c] = sc[f] * rs[r];
  }
}

extern "C" void kernel_launch(void* const* d_in, const int* in_sizes, int n_in,
                              void* d_out, int out_size, void* d_ws, size_t ws_size,
                              hipStream_t stream) {
  const float* x_in = (const float*)d_in[0];
  const int*   tidx = (const int*)d_in[1];
  const float* W1 = (const float*)d_in[2];
  const float* b1 = (const float*)d_in[3];
  const float* W2 = (const float*)d_in[4];
  const float* b2 = (const float*)d_in[5];
  const float* W3 = (const float*)d_in[6];
  const float* b3 = (const float*)d_in[7];
  const float* W4 = (const float*)d_in[8];
  const float* b4 = (const float*)d_in[9];
  const float* Wc = (const float*)d_in[10];
  const float* bc = (const float*)d_in[11];
  float* out = (float*)d_out;
  (void)in_sizes; (void)n_in; (void)out_size; (void)ws_size;

  char* ws = (char*)d_ws;
  __hip_bfloat16* xbf  = (__hip_bfloat16*)(ws + 0);         // 2,621,440
  __hip_bfloat16* w1t  = (__hip_bfloat16*)(ws + 2621440);   // 3,145,728 -> 5,767,168
  _Float16*       w2b  = (_Float16*)      (ws + 5767168);   // [1024][512] 1,048,576
  _Float16*       w3t  = (_Float16*)      (ws + 6815744);   // [1024][512] 1,048,576
  _Float16*       w4b  = (_Float16*)      (ws + 7864320);   // [1024][512] 1,048,576
  _Float16*       wct  = (_Float16*)      (ws + 8912896);   // [64][512]      65,536
  float*          b23  = (float*)         (ws + 8978432);   // [1024]          4,096
  float*          bc4  = (float*)         (ws + 8982528);   // [64]              256
  _Float16*       Hsb  = (_Float16*)      (ws + 8982784);   // [160][1024]   327,680
  _Float16*       w23t = (_Float16*)      (ws + 9310464);   // [1024][1024] 2,097,152
  _Float16*       w4ct = (_Float16*)      (ws + 11407616);  // [64][1024]    131,072
  float*          psc  = (float*)         (ws + 11538688);  // [16][160][64] 655,360

  // K0: all casts/transposes + bias folds (one launch)
  prep_all<<<4389, 256, 0, stream>>>(x_in, W1, W2, W3, W4, Wc, b2, b3, b4, bc,
                                     xbf, w1t, w2b, w3t, w4b, wct, b23, bc4);

  // K1: group compute (512 blocks) + overlapped weight-product GEMMs (272 blocks)
  group_wgemm<<<784, 256, 0, stream>>>(xbf, w1t, tidx, b1, Hsb,
                                       w3t, w2b, wct, w4b, w23t, w4ct);

  // K2: u = relu(Hs@W23 + b23) in LDS, + head partials -> psc
  mid_head<<<dim3(16, 2), 256, 0, stream>>>(Hsb, w23t, w4ct, b23, psc);

  // K3: 16-way reduce + softmax
  softmax2<<<2, 256, 0, stream>>>(psc, bc4, out);
}

// Round 5
// 139.566 us; speedup vs baseline: 1.1516x; 1.0512x over previous
//
#include <hip/hip_runtime.h>
#include <hip/hip_bf16.h>

// Problem constants (T,S,W,D,C,K) = (16,16,10,512,64,512)
#define T_  16
#define W_  10
#define D_  512
#define SW_ 160      // S*W
#define N1_ 1024     // 2*D
#define KT_ 512      // triplets per (t,w)

typedef __bf16 bf16x8 __attribute__((ext_vector_type(8)));
typedef _Float16 f16x8 __attribute__((ext_vector_type(8)));
typedef _Float16 h2v  __attribute__((ext_vector_type(2)));
typedef float  f32x4  __attribute__((ext_vector_type(4)));

// async global->LDS, 16B per lane (global addr per-lane; LDS dest = wave base + lane*16)
__device__ __forceinline__ void async16(const void* g, void* l) {
  __builtin_amdgcn_global_load_lds(
      (__attribute__((address_space(1))) void*)(g),
      (__attribute__((address_space(3))) void*)(l), 16, 0, 0);
}

__device__ __forceinline__ h2v bc2(unsigned u) { return __builtin_bit_cast(h2v, u); }
// relu on packed fp16 pair (v_pk_max_f16 with inline 0)
__device__ __forceinline__ h2v relu2(h2v a) {
  h2v r;
  asm("v_pk_max_f16 %0, %1, 0" : "=v"(r) : "v"(a));
  return r;
}

// ================= K0: prep_all — casts/transposes/bias-folds/idx-prescale, ONE launch
// [0,1280) x->bf16 | [1280,2816) W1^T bf16 | [2816,3328) W2 fp16 | [3328,3840) W3^T fp16
// [3840,4352) W4 fp16 | [4352,4384) Wc^T fp16 | [4384,4388) b23 | [4388] bc4
// [4389,4629) idx72 = tidx * 72 (pre-scaled byte offsets for the gather)
__global__ __launch_bounds__(256) void prep_all(
    const float* __restrict__ x_in, const float* __restrict__ W1,
    const float* __restrict__ W2, const float* __restrict__ W3,
    const float* __restrict__ W4, const float* __restrict__ Wc,
    const float* __restrict__ b2, const float* __restrict__ b3,
    const float* __restrict__ b4, const float* __restrict__ bc,
    const int* __restrict__ tidx,
    __hip_bfloat16* __restrict__ xbf, __hip_bfloat16* __restrict__ w1t,
    _Float16* __restrict__ w2b, _Float16* __restrict__ w3t,
    _Float16* __restrict__ w4b, _Float16* __restrict__ wct,
    float* __restrict__ b23, float* __restrict__ bc4,
    int* __restrict__ idx72)
{
  __shared__ float tile[32 * 33];
  const int b = blockIdx.x, tid = threadIdx.x;

  auto cast4h = [&](const float* src, _Float16* dst, int base) {
    int i = (base + tid) << 2;
    float4 v = *(const float4*)(src + i);
    __align__(8) _Float16 o4[4] = {(_Float16)v.x, (_Float16)v.y,
                                   (_Float16)v.z, (_Float16)v.w};
    *(uint2*)(dst + i) = *(const uint2*)o4;
  };
  auto tr32h = [&](const float* src, _Float16* dst, int R, int C, int rt, int ct) {
    int r0 = rt << 5, c0 = ct << 5;
    int c = tid & 31, rr = tid >> 5;
#pragma unroll
    for (int i = 0; i < 4; ++i) {
      int r = rr + i * 8;
      tile[r * 33 + c] = src[(size_t)(r0 + r) * C + c0 + c];
    }
    __syncthreads();
#pragma unroll
    for (int i = 0; i < 4; ++i) {
      int r = rr + i * 8;
      dst[(size_t)(c0 + r) * R + r0 + c] = (_Float16)tile[c * 33 + r];
    }
  };

  if (b < 1280) {
    int i = (b * 256 + tid) << 2;
    float4 v = *(const float4*)(x_in + i);
    __align__(8) __hip_bfloat16 o4[4];
    o4[0] = __float2bfloat16(v.x); o4[1] = __float2bfloat16(v.y);
    o4[2] = __float2bfloat16(v.z); o4[3] = __float2bfloat16(v.w);
    *(uint2*)(xbf + i) = *(const uint2*)o4;
  } else if (b < 2816) {
    int q = b - 1280;
    int r0 = (q >> 5) << 5, c0 = (q & 31) << 5;
    int c = tid & 31, rr = tid >> 5;
#pragma unroll
    for (int i = 0; i < 4; ++i) {
      int r = rr + i * 8;
      tile[r * 33 + c] = W1[(size_t)(r0 + r) * 1024 + c0 + c];
    }
    __syncthreads();
#pragma unroll
    for (int i = 0; i < 4; ++i) {
      int r = rr + i * 8;
      w1t[(size_t)(c0 + r) * 1536 + r0 + c] = __float2bfloat16(tile[c * 33 + r]);
    }
  } else if (b < 3328) {
    cast4h(W2, w2b, (b - 2816) * 256);
  } else if (b < 3840) {
    int q = b - 3328; tr32h(W3, w3t, 512, 1024, q >> 5, q & 31);
  } else if (b < 4352) {
    cast4h(W4, w4b, (b - 3840) * 256);
  } else if (b < 4384) {
    int q = b - 4352; tr32h(Wc, wct, 512, 64, q >> 1, q & 1);
  } else if (b < 4388) {
    int c = (b - 4384) * 256 + tid;
    float s = 0.f;
#pragma unroll 32
    for (int j = 0; j < 512; ++j) s += b2[j] * W3[(size_t)j * 1024 + c];
    b23[c] = 512.f * s + b3[c];
  } else if (b < 4389) {
    if (tid < 64) {
      float s = 0.f;
#pragma unroll 32
      for (int j = 0; j < 512; ++j) s += b4[j] * Wc[(size_t)j * 64 + tid];
      bc4[tid] = s + bc[tid];
    }
  } else {
    int i = ((b - 4389) * 256 + tid) << 2;      // 61440 int4 total
    int4 v = *(const int4*)(tidx + i);
    *(int4*)(idx72 + i) = make_int4(v.x * 72, v.y * 72, v.z * 72, v.w * 72);
  }
}

// ================= K1: group blocks 0..511 (BK=64 GEMM + barrier-free wave-per-w
// gather) + fused weight-product GEMM blocks 512..783. smem 34560 -> 4 blocks/CU.
__global__ __launch_bounds__(256, 3) void group_wgemm(
    const __hip_bfloat16* __restrict__ xbf,   // [16][160][512]
    const __hip_bfloat16* __restrict__ w1t,   // [1024][1536]
    const int* __restrict__ idx72,            // [16][10][3][512] pre-scaled *72
    const float* __restrict__ b1,             // [1024]
    _Float16* __restrict__ Hsb,               // [160][1024] fp16
    const _Float16* __restrict__ w3t,         // [1024][512]
    const _Float16* __restrict__ w2b,         // [1024][512]
    const _Float16* __restrict__ wct,         // [64][512]
    const _Float16* __restrict__ w4b,         // [1024][512]
    _Float16* __restrict__ w23t,              // [1024][1024]
    _Float16* __restrict__ w4ct)              // [64][1024]
{
  __shared__ __align__(16) char smem[34560];
  const int bx = blockIdx.x;
  const int tid = threadIdx.x;
  const int ln = tid & 63, wv = tid >> 6;
  const int col16 = ln & 15, quad = ln >> 4;

  if (bx >= 512) {
    // ---- weight GEMM: out[m][n] = sum_k A[m][k]*Bt[n][k], K=512 fp16, 64x64 tile
    const int b = bx - 512;
    const _Float16 *A, *Bt;
    _Float16* out;
    int m0, n0;
    if (b < 256) { A = w3t; Bt = w2b; out = w23t; m0 = (b >> 4) << 6; n0 = (b & 15) << 6; }
    else         { A = wct; Bt = w4b; out = w4ct; m0 = 0;             n0 = (b - 256) << 6; }
    char* Abuf = smem;              // 64 x 256B = 16384
    char* Bbuf = smem + 16384;      // 16384

    f32x4 acc[4];
#pragma unroll
    for (int a = 0; a < 4; ++a) acc[a] = (f32x4){0.f, 0.f, 0.f, 0.f};

#pragma unroll 1
    for (int kk = 0; kk < 512; kk += 128) {
      __syncthreads();
#pragma unroll
      for (int p = 0; p < 4; ++p) {           // A: 64 rows x 16 chunks
        int i = p * 256 + tid, r = i >> 4, q = i & 15;
        async16(A + (size_t)(m0 + r) * 512 + kk + ((q ^ (r & 7)) << 3), Abuf + (i << 4));
      }
#pragma unroll
      for (int p = 0; p < 4; ++p) {           // B: 64 rows x 16 chunks
        int i = p * 256 + tid, r = i >> 4, q = i & 15;
        async16(Bt + (size_t)(n0 + r) * 512 + kk + ((q ^ (r & 7)) << 3), Bbuf + (i << 4));
      }
      __syncthreads();

#pragma unroll
      for (int ks = 0; ks < 4; ++ks) {
        const int qq = (ks << 2) + quad;
        const int rn = (wv << 4) + col16;
        f16x8 bfm = *(const f16x8*)(Bbuf + rn * 256 + ((qq ^ (rn & 7)) << 4));
#pragma unroll
        for (int a = 0; a < 4; ++a) {
          int rm = (a << 4) + col16;
          f16x8 af = *(const f16x8*)(Abuf + rm * 256 + ((qq ^ (rm & 7)) << 4));
          acc[a] = __builtin_amdgcn_mfma_f32_16x16x32_f16(af, bfm, acc[a], 0, 0, 0);
        }
      }
    }

    const int n = n0 + (wv << 4) + col16;
#pragma unroll
    for (int a = 0; a < 4; ++a)
#pragma unroll
      for (int r = 0; r < 4; ++r) {
        size_t row = m0 + (a << 4) + (quad << 2) + r;
        out[row * 1024 + n] = (_Float16)acc[a][r];
      }
    return;
  }

  // ---------------- group part ----------------
  char* Abuf  = smem;                      // [0, 20480)  phase 1 (BK=64, 160x128B)
  char* Bbuf  = smem + 20480;              // [20480, 32768) phase 1 (96x128B)
  char* Ptile = smem;                      // [0, 34560)  phase 2

  const int t   = bx >> 5;
  const int nt  = bx & 31;
  const int n0  = nt << 5;                 // 32-col output window

  const int wr = wv >> 1, wc = wv & 1;     // 2x2 wave grid: 80 rows x 48 cols each

  const __hip_bfloat16* xt = xbf + (size_t)t * (SW_ * D_);

  int aoff[5], lofA[5];
#pragma unroll
  for (int s = 0; s < 5; ++s) {            // A: 160 rows x 8 chunks = 1280
    int i = s * 256 + tid, r = i >> 3, q = i & 7;
    aoff[s] = r * 512 + ((q ^ (r & 7)) << 3);
    lofA[s] = i << 4;
  }
  int boff[3], lofB[3];
#pragma unroll
  for (int s = 0; s < 3; ++s) {            // B: 96 rows (j*32+nc) x 8 chunks = 768
    int i = s * 256 + tid, r = i >> 3, q = i & 7;
    int nc = r & 31, j = r >> 5;
    boff[s] = (n0 + nc) * 1536 + j * 512 + ((q ^ (r & 7)) << 3);
    lofB[s] = i << 4;
  }

  f32x4 acc[5][3];
#pragma unroll
  for (int a = 0; a < 5; ++a)
#pragma unroll
    for (int b = 0; b < 3; ++b)
      acc[a][b] = (f32x4){0.f, 0.f, 0.f, 0.f};

  // ---- phase 1: K-loop, BK=64 (8 iters)
#pragma unroll 1
  for (int kk = 0; kk < 512; kk += 64) {
    __syncthreads();
#pragma unroll
    for (int s = 0; s < 5; ++s) async16(xt + aoff[s] + kk, Abuf + lofA[s]);
#pragma unroll
    for (int s = 0; s < 3; ++s) async16(w1t + boff[s] + kk, Bbuf + lofB[s]);
    __syncthreads();

#pragma unroll
    for (int ks = 0; ks < 2; ++ks) {
      const int qq = (ks << 2) + quad;
      bf16x8 af[5], bfr[3];
#pragma unroll
      for (int a = 0; a < 5; ++a) {
        int rm = wr * 80 + a * 16 + col16;
        af[a] = *(const bf16x8*)(Abuf + rm * 128 + ((qq ^ (rm & 7)) << 4));
      }
#pragma unroll
      for (int b = 0; b < 3; ++b) {
        int rn = wc * 48 + b * 16 + col16;
        bfr[b] = *(const bf16x8*)(Bbuf + rn * 128 + ((qq ^ (rn & 7)) << 4));
      }
#pragma unroll
      for (int a = 0; a < 5; ++a)
#pragma unroll
        for (int b = 0; b < 3; ++b)
          acc[a][b] = __builtin_amdgcn_mfma_f32_16x16x32_bf16(af[a], bfr[b], acc[a][b], 0, 0, 0);
    }
  }

  __syncthreads();   // all staging reads done; smem now becomes Ptile

  // ---- write P to LDS as fp16, layout [j][sw][nc] stride 72 B; fold b1 into j==2
#pragma unroll
  for (int b = 0; b < 3; ++b) {
    int c = wc * 48 + b * 16 + col16;       // 0..95; j constant per (wc,b) chunk
    int j = c >> 5, nc = c & 31;
    float bv = (j == 2) ? b1[n0 + nc] : 0.f;
#pragma unroll
    for (int a = 0; a < 5; ++a) {
      int mb = wr * 80 + a * 16 + quad * 4;
#pragma unroll
      for (int r = 0; r < 4; ++r)
        *(_Float16*)(Ptile + (j * 160 + mb + r) * 72 + nc * 2) =
            (_Float16)(acc[a][b][r] + bv);
    }
  }
  __syncthreads();                          // Ptile visible to all waves

  // ---- phase 2: barrier-free wave-per-w gather. Wave wv handles w = wv, wv+4, wv+8.
  // Lane: kq8 = ln>>3 covers k in [kq8*64, +64); nq = ln&7 covers cols nq*4..+3.
  const int kq8 = ln >> 3, nq = ln & 7;
  const char* Pt0 = Ptile + (nq << 3);
  const char* Pt1 = Pt0 + 11520;
  const char* Pt2 = Pt0 + 23040;
  const int* ibase = idx72 + (size_t)t * 10 * 1536 + (kq8 << 6);

#pragma unroll 1
  for (int w = wv; w < 10; w += 4) {
    const int* c0 = ibase + w * 1536;
    const int* c1 = c0 + 512;
    const int* c2 = c0 + 1024;
    f32x4 a4 = (f32x4){0.f, 0.f, 0.f, 0.f};
#pragma unroll
    for (int c4 = 0; c4 < 4; ++c4) {        // flush fp16 accum to f32 every 16 k
      h2v acc01 = (h2v)0, acc23 = (h2v)0;
#pragma unroll
      for (int u = 0; u < 4; ++u) {
        const int off = (c4 << 4) + (u << 2);
        int4 i0 = *(const int4*)(c0 + off);
        int4 i1 = *(const int4*)(c1 + off);
        int4 i2 = *(const int4*)(c2 + off);
#define STEP(IA, IB, IC)                                                  \
        {                                                                 \
          uint2 p0 = *(const uint2*)(Pt0 + (IA));                         \
          uint2 p1 = *(const uint2*)(Pt1 + (IB));                         \
          uint2 p2 = *(const uint2*)(Pt2 + (IC));                         \
          h2v sx = bc2(p0.x) + bc2(p1.x) + bc2(p2.x);                     \
          h2v sy = bc2(p0.y) + bc2(p1.y) + bc2(p2.y);                     \
          acc01 += relu2(sx);                                             \
          acc23 += relu2(sy);                                             \
        }
        STEP(i0.x, i1.x, i2.x)
        STEP(i0.y, i1.y, i2.y)
        STEP(i0.z, i1.z, i2.z)
        STEP(i0.w, i1.w, i2.w)
#undef STEP
      }
      a4.x += (float)acc01.x; a4.y += (float)acc01.y;
      a4.z += (float)acc23.x; a4.w += (float)acc23.y;
    }

    // reduce across kq8 (lane bits 3..5) — intra-wave only
#pragma unroll
    for (int off = 8; off <= 32; off <<= 1) {
      a4.x += __shfl_xor(a4.x, off);
      a4.y += __shfl_xor(a4.y, off);
      a4.z += __shfl_xor(a4.z, off);
      a4.w += __shfl_xor(a4.w, off);
    }
    if (kq8 == 0) {
      __align__(8) _Float16 o4[4] = {(_Float16)a4.x, (_Float16)a4.y,
                                     (_Float16)a4.z, (_Float16)a4.w};
      *(uint2*)(Hsb + (size_t)(t * 10 + w) * N1_ + n0 + (nq << 2)) =
          *(const uint2*)o4;
    }
  }
}

// ================= K2: mid_head — u = relu(Hs@W23 + b23) (kept in LDS only),
// then partial head: psc[nblk][160][64] = u_tile @ W4c_slice^T. Grid (16,2).
__global__ __launch_bounds__(256) void mid_head(
    const _Float16* __restrict__ A,          // Hsb [160][1024]
    const _Float16* __restrict__ Bt,         // w23t [1024][1024]
    const _Float16* __restrict__ W4c,        // w4ct [64][1024]
    const float* __restrict__ bias,          // b23
    float* __restrict__ psc)                 // [16][160][64] f32
{
  __shared__ __align__(16) char Abuf[40960];  // 80 rows x 512 B
  __shared__ __align__(16) char Bbuf[32768];  // 64 rows x 512 B
  __shared__ __align__(16) char Hbuf[8192];   // W4c slice: 64 rows x 128 B
  const int tid = threadIdx.x;
  const int n0 = blockIdx.x << 6;
  const int m0 = blockIdx.y * 80;
  const int ln = tid & 63, wv = tid >> 6;
  const int col16 = ln & 15, quad = ln >> 4;

  // stage the W4c slice early (drained by first K-loop barrier, free overlap)
#pragma unroll
  for (int p = 0; p < 2; ++p) {             // 64 rows x 8 chunks = 512
    int i = p * 256 + tid, r = i >> 3, q = i & 7;
    async16(W4c + (size_t)r * 1024 + n0 + ((q ^ (r & 7)) << 3), Hbuf + (i << 4));
  }

  f32x4 acc[5];
#pragma unroll
  for (int a = 0; a < 5; ++a) acc[a] = (f32x4){0.f, 0.f, 0.f, 0.f};

#pragma unroll 1
  for (int kk = 0; kk < 1024; kk += 256) {
    __syncthreads();
#pragma unroll
    for (int p = 0; p < 10; ++p) {          // A: 80 rows x 32 chunks
      int i = p * 256 + tid, r = i >> 5, q = i & 31;
      async16(A + (size_t)(m0 + r) * 1024 + kk + ((q ^ (r & 7)) << 3), Abuf + (i << 4));
    }
#pragma unroll
    for (int p = 0; p < 8; ++p) {           // B: 64 rows x 32 chunks
      int i = p * 256 + tid, r = i >> 5, q = i & 31;
      async16(Bt + (size_t)(n0 + r) * 1024 + kk + ((q ^ (r & 7)) << 3), Bbuf + (i << 4));
    }
    __syncthreads();

#pragma unroll
    for (int ks = 0; ks < 8; ++ks) {
      const int qq = (ks << 2) + quad;
      const int rn = (wv << 4) + col16;
      f16x8 bfm = *(const f16x8*)(Bbuf + rn * 512 + ((qq ^ (rn & 7)) << 4));
#pragma unroll
      for (int a = 0; a < 5; ++a) {
        int rm = (a << 4) + col16;
        f16x8 af = *(const f16x8*)(Abuf + rm * 512 + ((qq ^ (rm & 7)) << 4));
        acc[a] = __builtin_amdgcn_mfma_f32_16x16x32_f16(af, bfm, acc[a], 0, 0, 0);
      }
    }
  }

  // ---- u tile -> LDS (fp16, 80 rows x 128 B, chunk-swizzled); no global write
  const float bb = bias[n0 + (wv << 4) + col16];
  __syncthreads();                          // all Abuf/Bbuf reads done
  char* U = Abuf;                           // overlay
  const int cl = (wv << 4) + col16;         // local col 0..63
#pragma unroll
  for (int a = 0; a < 5; ++a)
#pragma unroll
    for (int r = 0; r < 4; ++r) {
      float v = fmaxf(acc[a][r] + bb, 0.f);
      int m = (a << 4) + (quad << 2) + r;
      *(_Float16*)(U + m * 128 + (((cl >> 3) ^ (m & 7)) << 4) + ((cl & 7) << 1)) =
          (_Float16)v;
    }
  __syncthreads();

  // ---- head partial: 80x64 u-tile @ 64x64 W4c-slice^T (K=64 -> 2 MFMA steps)
  f32x4 acc2[5];
#pragma unroll
  for (int a = 0; a < 5; ++a) acc2[a] = (f32x4){0.f, 0.f, 0.f, 0.f};
#pragma unroll
  for (int ks = 0; ks < 2; ++ks) {
    const int qq = (ks << 2) + quad;
    const int rn = (wv << 4) + col16;
    f16x8 bfm = *(const f16x8*)(Hbuf + rn * 128 + ((qq ^ (rn & 7)) << 4));
#pragma unroll
    for (int a = 0; a < 5; ++a) {
      int rm = (a << 4) + col16;
      f16x8 af = *(const f16x8*)(U + rm * 128 + ((qq ^ (rm & 7)) << 4));
      acc2[a] = __builtin_amdgcn_mfma_f32_16x16x32_f16(af, bfm, acc2[a], 0, 0, 0);
    }
  }
  float* po = psc + ((size_t)blockIdx.x * 160 + m0) * 64;
#pragma unroll
  for (int a = 0; a < 5; ++a)
#pragma unroll
    for (int r = 0; r < 4; ++r)
      po[((a << 4) + (quad << 2) + r) * 64 + (wv << 4) + col16] = acc2[a][r];
}

// ================= K3: softmax over 16-way partial sums. Grid 2: 80 rows/block.
__global__ __launch_bounds__(256) void softmax2(
    const float* __restrict__ psc,           // [16][160][64]
    const float* __restrict__ bc4,
    float* __restrict__ out)                 // [160][64]
{
  __shared__ float sc[80 * 64];
  __shared__ float rs[80];
  const int tid = threadIdx.x;
  const int m0 = blockIdx.x * 80;

#pragma unroll
  for (int p = 0; p < 5; ++p) {
    int f = p * 256 + tid;                   // 1280 = 80 rows x 16 col-groups
    int r = f >> 4, cq = f & 15;
    f32x4 s = (f32x4){0.f, 0.f, 0.f, 0.f};
#pragma unroll
    for (int j = 0; j < 16; ++j)
      s += *(const f32x4*)(psc + ((size_t)(j * 160) + m0 + r) * 64 + (cq << 2));
    s += *(const f32x4*)(bc4 + (cq << 2));
    *(f32x4*)(sc + r * 64 + (cq << 2)) = s;
  }
  __syncthreads();

  if (tid < 80) {
    float m = -1e30f;
    for (int c = 0; c < 64; ++c) m = fmaxf(m, sc[tid * 64 + c]);
    float s = 0.f;
    for (int c = 0; c < 64; ++c) {
      float e = expf(sc[tid * 64 + c] - m);
      sc[tid * 64 + c] = e;
      s += e;
    }
    rs[tid] = 1.f / s;
  }
  __syncthreads();
#pragma unroll
  for (int p = 0; p < 20; ++p) {
    int f = p * 256 + tid, r = f >> 6, c = f & 63;
    out[(size_t)(m0 + r) * 64 + c] = sc[f] * rs[r];
  }
}

extern "C" void kernel_launch(void* const* d_in, const int* in_sizes, int n_in,
                              void* d_out, int out_size, void* d_ws, size_t ws_size,
                              hipStream_t stream) {
  const float* x_in = (const float*)d_in[0];
  const int*   tidx = (const int*)d_in[1];
  const float* W1 = (const float*)d_in[2];
  const float* b1 = (const float*)d_in[3];
  const float* W2 = (const float*)d_in[4];
  const float* b2 = (const float*)d_in[5];
  const float* W3 = (const float*)d_in[6];
  const float* b3 = (const float*)d_in[7];
  const float* W4 = (const float*)d_in[8];
  const float* b4 = (const float*)d_in[9];
  const float* Wc = (const float*)d_in[10];
  const float* bc = (const float*)d_in[11];
  float* out = (float*)d_out;
  (void)in_sizes; (void)n_in; (void)out_size; (void)ws_size;

  char* ws = (char*)d_ws;
  __hip_bfloat16* xbf  = (__hip_bfloat16*)(ws + 0);         // 2,621,440
  __hip_bfloat16* w1t  = (__hip_bfloat16*)(ws + 2621440);   // 3,145,728 -> 5,767,168
  _Float16*       w2b  = (_Float16*)      (ws + 5767168);   // [1024][512] 1,048,576
  _Float16*       w3t  = (_Float16*)      (ws + 6815744);   // [1024][512] 1,048,576
  _Float16*       w4b  = (_Float16*)      (ws + 7864320);   // [1024][512] 1,048,576
  _Float16*       wct  = (_Float16*)      (ws + 8912896);   // [64][512]      65,536
  float*          b23  = (float*)         (ws + 8978432);   // [1024]          4,096
  float*          bc4  = (float*)         (ws + 8982528);   // [64]              256
  _Float16*       Hsb  = (_Float16*)      (ws + 8982784);   // [160][1024]   327,680
  _Float16*       w23t = (_Float16*)      (ws + 9310464);   // [1024][1024] 2,097,152
  _Float16*       w4ct = (_Float16*)      (ws + 11407616);  // [64][1024]    131,072
  float*          psc  = (float*)         (ws + 11538688);  // [16][160][64] 655,360
  int*            idx72= (int*)           (ws + 12194048);  // [16][10][3][512] 983,040

  // K0: all casts/transposes + bias folds + idx pre-scale (one launch)
  prep_all<<<4629, 256, 0, stream>>>(x_in, W1, W2, W3, W4, Wc, b2, b3, b4, bc, tidx,
                                     xbf, w1t, w2b, w3t, w4b, wct, b23, bc4, idx72);

  // K1: group compute (512 blocks) + overlapped weight-product GEMMs (272 blocks)
  group_wgemm<<<784, 256, 0, stream>>>(xbf, w1t, idx72, b1, Hsb,
                                       w3t, w2b, wct, w4b, w23t, w4ct);

  // K2: u = relu(Hs@W23 + b23) in LDS, + head partials -> psc
  mid_head<<<dim3(16, 2), 256, 0, stream>>>(Hsb, w23t, w4ct, b23, psc);

  // K3: 16-way reduce + softmax
  softmax2<<<2, 256, 0, stream>>>(psc, bc4, out);
}